// Round 7
// baseline (463.018 us; speedup 1.0000x reference)
//
#include <hip/hip_runtime.h>
#include <cstdint>
#include <cstddef>

#define BN_EPSF 1e-5f

constexpr int B_  = 32, N_ = 512, F_ = 1024, E_ = 32768;
constexpr int H1_ = 512, H2_ = 256, H3_ = 128, NC_ = 8, EC_ = 10;
constexpr int M_  = B_ * N_;      // 16384 node rows
constexpr int NE_ = B_ * E_;      // 1048576 edges

typedef short bf16x8 __attribute__((ext_vector_type(8)));
typedef float f32x4  __attribute__((ext_vector_type(4)));

__device__ __forceinline__ short f2bf(float f) {
  union { float f; unsigned u; } v; v.f = f;
  unsigned r = v.u + 0x7fffu + ((v.u >> 16) & 1u);   // RNE
  return (short)(r >> 16);
}
// HW packed f32->bf16 RNE: a -> low16, b -> high16
__device__ __forceinline__ unsigned cvtpk(float a, float b) {
  unsigned r;
  asm("v_cvt_pk_bf16_f32 %0, %1, %2" : "=v"(r) : "v"(a), "v"(b));
  return r;
}

#define GLDS(gp, lp) __builtin_amdgcn_global_load_lds( \
    (const __attribute__((address_space(1))) void*)(gp), \
    (__attribute__((address_space(3))) void*)(lp), 16, 0, 0)

#define MFMA(a, b, c) __builtin_amdgcn_mfma_f32_16x16x32_bf16((a), (b), (c), 0, 0, 0)

// ---------------------------------------------------------------------------
// prep: roi fp32->bf16 (8192) | 3x weight transpose (672) | attr pack (64).
// ---------------------------------------------------------------------------
__device__ __forceinline__ void wt_body(
    const float* __restrict__ W, short* __restrict__ Wt, int K, int N,
    int bx, int by, float (*s)[33])
{
  const int tx = threadIdx.x & 31, ty = threadIdx.x >> 5;
  const int k0 = by * 32, n0 = bx * 32;
#pragma unroll
  for (int r = 0; r < 4; r++)
    s[ty * 4 + r][tx] = W[(size_t)(k0 + ty * 4 + r) * N + n0 + tx];
  __syncthreads();
#pragma unroll
  for (int r = 0; r < 4; r++)
    Wt[(size_t)(n0 + ty * 4 + r) * K + k0 + tx] = f2bf(s[tx][ty * 4 + r]);
}

__global__ __launch_bounds__(256) void k_prep(
    const float* __restrict__ roi, ushort* __restrict__ roiB,
    const float* __restrict__ w1, short* __restrict__ w1t,
    const float* __restrict__ w2, short* __restrict__ w2t,
    const float* __restrict__ w3, short* __restrict__ w3t,
    const float* __restrict__ bbox, const float* __restrict__ dir,
    const float* __restrict__ pri, ushort* __restrict__ attrT)
{
  __shared__ float s[32][33];
  const int bx = blockIdx.x;
  if (bx < 8192) {                       // roi -> bf16, 8 elems/thread
    int i = bx * 256 + threadIdx.x;
    float4 a = *(const float4*)(roi + (size_t)i * 8);
    float4 b = *(const float4*)(roi + (size_t)i * 8 + 4);
    unsigned o[4];
    o[0] = cvtpk(a.x, a.y); o[1] = cvtpk(a.z, a.w);
    o[2] = cvtpk(b.x, b.y); o[3] = cvtpk(b.z, b.w);
    *(uint4*)(roiB + (size_t)i * 8) = *(uint4*)o;
  } else if (bx < 8704) {                // w1t: K=1024 N=512
    int idx = bx - 8192; wt_body(w1, w1t, F_, H1_, idx & 15, idx >> 4, s);
  } else if (bx < 8832) {                // w2t: K=512 N=256
    int idx = bx - 8704; wt_body(w2, w2t, H1_, H2_, idx & 7, idx >> 3, s);
  } else if (bx < 8864) {                // w3t: K=256 N=128
    int idx = bx - 8832; wt_body(w3, w3t, H2_, H3_, idx & 3, idx >> 2, s);
  } else {                               // attr pack: 1 node/thread
    int gi = (bx - 8864) * 256 + threadIdx.x;
    const float inv = 1.0f / 1024.0f;
    float4 bv = *(const float4*)(bbox + (size_t)gi * 4);
    float4 dv = *(const float4*)(dir + (size_t)gi * 4);
    float pp = pri[gi];
    uint4 lo, hi;
    lo.x = cvtpk(bv.x * inv, bv.y * inv); lo.y = cvtpk(bv.z * inv, bv.w * inv);
    lo.z = cvtpk(dv.x, dv.y);             lo.w = cvtpk(dv.z, dv.w);
    hi.x = cvtpk(pp, 0.f); hi.y = 0; hi.z = 0; hi.w = 0;
    *(uint4*)(attrT + (size_t)gi * 16)     = lo;
    *(uint4*)(attrT + (size_t)gi * 16 + 8) = hi;
  }
}

// ---------------------------------------------------------------------------
// Edge-path layer transition, fully in registers.
// ---------------------------------------------------------------------------
__device__ __forceinline__ void relu_pack_shuf(
    const f32x4 (&acc)[4], int la, int lb, bool lo32, bf16x8 (&out)[2])
{
  unsigned plo[4], phi[4];
#pragma unroll
  for (int t = 0; t < 4; t++) {
    plo[t] = cvtpk(fmaxf(acc[t][0], 0.f), fmaxf(acc[t][1], 0.f));
    phi[t] = cvtpk(fmaxf(acc[t][2], 0.f), fmaxf(acc[t][3], 0.f));
  }
#pragma unroll
  for (int ks = 0; ks < 2; ks++) {
    unsigned w0a = (unsigned)__shfl((int)plo[2 * ks], la);
    unsigned w0b = (unsigned)__shfl((int)plo[2 * ks + 1], la);
    unsigned w1a = (unsigned)__shfl((int)phi[2 * ks], la);
    unsigned w1b = (unsigned)__shfl((int)phi[2 * ks + 1], la);
    unsigned w2a = (unsigned)__shfl((int)plo[2 * ks], lb);
    unsigned w2b = (unsigned)__shfl((int)plo[2 * ks + 1], lb);
    unsigned w3a = (unsigned)__shfl((int)phi[2 * ks], lb);
    unsigned w3b = (unsigned)__shfl((int)phi[2 * ks + 1], lb);
    union { unsigned u[4]; bf16x8 v; } t;
    t.u[0] = lo32 ? w0a : w0b;
    t.u[1] = lo32 ? w1a : w1b;
    t.u[2] = lo32 ? w2a : w2b;
    t.u[3] = lo32 ? w3a : w3b;
    out[ks] = t.v;
  }
}

// ---------------------------------------------------------------------------
// fused edge+L1 kernel. Grid 1536, 2:1 interleave. L1: BK=64 + chunk-XOR
// swizzle (R4-verified). Edge: attr gather from TWO split 16B-row LDS tables
// (sA0 = node chunk0, sA1 = chunk1): bank group = n%8 -> full 8-group spread
// at 16KB total (was 24KB @48B rows). Arena 32KB -> 5 blocks/CU (was 4):
// edge chain is latency-bound at 2 waves/SIMD, occupancy is the lever.
// ---------------------------------------------------------------------------
__global__ __launch_bounds__(256, 5) void k_fused(
    // edge args
    const ushort* __restrict__ attrT, const int* __restrict__ eidx,
    const float* __restrict__ ew1, const float* __restrict__ eb1,
    const float* __restrict__ ew2, const float* __restrict__ eb2,
    const float* __restrict__ eow, const float* __restrict__ eob,
    float* __restrict__ out_edge,
    // L1 args
    const short* __restrict__ roiB, const short* __restrict__ w1t,
    const float* __restrict__ b1, const float* __restrict__ g1,
    const float* __restrict__ bb1, const float* __restrict__ rm1,
    const float* __restrict__ rv1, short* __restrict__ h1)
{
  __shared__ __align__(16) char arena[32768];

  const int bx = blockIdx.x;
  const int rsel = bx % 3;
  const int tid  = threadIdx.x;
  const int wave = tid >> 6, lane = tid & 63;
  const int lm = lane & 15;

  if (rsel == 2) {
    // ================= L1 GEMM block (BK=64, swizzled) =================
    const int lb = bx / 3;
    short* As = (short*)arena;             // 128 x 64 (128B rows, swizzled)
    short* Bs = (short*)(arena + 16384);   // 128 x 64
    const int m0 = (lb >> 2) * 128, n0 = (lb & 3) * 128;
    const int wm = wave >> 1, wn = wave & 1;
    const int q  = lane >> 4;
    const int srow = tid >> 3;
    const int sko  = ((tid & 7) ^ (srow & 7)) * 8;

    f32x4 acc[4][4] = {};
    for (int k0 = 0; k0 < F_; k0 += 64) {
#pragma unroll
      for (int it = 0; it < 4; it++)
        GLDS(roiB + (size_t)(m0 + it * 32 + srow) * F_ + k0 + sko,
             (char*)As + it * 4096 + wave * 1024);
#pragma unroll
      for (int it = 0; it < 4; it++)
        GLDS(w1t + (size_t)(n0 + it * 32 + srow) * F_ + k0 + sko,
             (char*)Bs + it * 4096 + wave * 1024);
      __syncthreads();

#pragma unroll
      for (int ks = 0; ks < 2; ks++) {
        const int co = (((ks * 4 + q) ^ (lm & 7)) * 8);   // swizzled k-chunk
        bf16x8 af[4], bfr[4];
#pragma unroll
        for (int t = 0; t < 4; t++) {
          af[t]  = *(const bf16x8*)&As[(wm * 64 + t * 16 + lm) * 64 + co];
          bfr[t] = *(const bf16x8*)&Bs[(wn * 64 + t * 16 + lm) * 64 + co];
        }
#pragma unroll
        for (int ti = 0; ti < 4; ti++)
#pragma unroll
          for (int tj = 0; tj < 4; tj++)
            acc[ti][tj] = MFMA(af[ti], bfr[tj], acc[ti][tj]);
      }
      __syncthreads();
    }
#pragma unroll
    for (int tj = 0; tj < 4; tj++) {
      const int col = n0 + wn * 64 + tj * 16 + lm;
      const float bi = b1[col];
      float s = g1[col] * rsqrtf(rv1[col] + BN_EPSF);
      float t = bb1[col] - rm1[col] * s;
#pragma unroll
      for (int ti = 0; ti < 4; ti++) {
        const int rbase = m0 + wm * 64 + ti * 16 + ((lane >> 4) << 2);
#pragma unroll
        for (int r = 0; r < 4; r += 2) {
          float va = fmaf(acc[ti][tj][r]     + bi, s, t);
          float vb = fmaf(acc[ti][tj][r + 1] + bi, s, t);
          unsigned p = cvtpk(fmaxf(va, 0.f), fmaxf(vb, 0.f));
          h1[(size_t)(rbase + r)     * H1_ + col] = (short)p;
          h1[(size_t)(rbase + r + 1) * H1_ + col] = (short)(p >> 16);
        }
      }
    }
    return;
  }

  // ================= edge block =================
  const int eb    = (bx / 3) * 2 + rsel;     // 0..1023
  const int batch = eb >> 5;                 // one graph-batch per block
  const int q     = lane >> 4;

  short*  sW1 = (short*)arena;               // 64 x 32 (K remapped/padded)
  short*  sW2 = (short*)(arena + 4096);      // 64 x 64
  short*  sW3 = (short*)(arena + 12288);     // 16 x 64 (rows 10..15 zero)
  ushort* sA0 = (ushort*)(arena + 14336);    // 512 x 8: node attr chunk 0
  ushort* sA1 = (ushort*)(arena + 22528);    // 512 x 8: node attr chunk 1

  // ---- stage weights + split attr tables (once per block) ----
  // W1 K-layout: k<9 = src attrs, 16<=k<25 = dst attrs, rest zero.
  for (int i = tid; i < 2048; i += 256) {
    int n = i >> 5, k = i & 31;
    short v = 0;
    if (k < 9)                  v = f2bf(ew1[k * 64 + n]);
    else if (k >= 16 && k < 25) v = f2bf(ew1[(k - 7) * 64 + n]);
    sW1[i] = v;
  }
  for (int i = tid; i < 4096; i += 256) {
    int n = i >> 6, k = i & 63;
    sW2[i] = f2bf(ew2[k * 64 + n]);
  }
  for (int i = tid; i < 1024; i += 256) {
    int n = i >> 6, k = i & 63;
    sW3[i] = (n < 10) ? f2bf(eow[k * 10 + n]) : (short)0;
  }
  {
    const ushort* atg = attrT + (size_t)batch * 512 * 16;
    for (int n = tid; n < 512; n += 256) {
      uint4 lo = *(const uint4*)(atg + n * 16);
      uint4 hi = *(const uint4*)(atg + n * 16 + 8);
      *(uint4*)&sA0[n * 8] = lo;
      *(uint4*)&sA1[n * 8] = hi;
    }
  }
  __syncthreads();   // the ONLY barrier in this block

  // ---- weight fragments + biases into registers (ONCE per block) ----
  bf16x8 fW1[4], fW2[4][2], fW3[2];
#pragma unroll
  for (int t = 0; t < 4; t++)
    fW1[t] = *(const bf16x8*)&sW1[(t * 16 + lm) * 32 + q * 8];
#pragma unroll
  for (int t = 0; t < 4; t++)
#pragma unroll
    for (int ks = 0; ks < 2; ks++)
      fW2[t][ks] = *(const bf16x8*)&sW2[(t * 16 + lm) * 64 + ks * 32 + q * 8];
#pragma unroll
  for (int ks = 0; ks < 2; ks++)
    fW3[ks] = *(const bf16x8*)&sW3[lm * 64 + ks * 32 + q * 8];

  f32x4 b1q[4], b2q[4], boq;
#pragma unroll
  for (int t = 0; t < 4; t++) {
    b1q[t] = *(const f32x4*)(eb1 + t * 16 + q * 4);
    b2q[t] = *(const f32x4*)(eb2 + t * 16 + q * 4);
  }
#pragma unroll
  for (int r = 0; r < 4; r++)
    boq[r] = (q * 4 + r < 10) ? eob[q * 4 + r] : 0.f;

  const int  la   = (lane & 15) | ((lane & 16) << 1);   // e + 32*(kq&1)
  const int  lbn  = la + 16;
  const bool lo32 = (lane < 32);
  const int* ip   = eidx + (size_t)batch * 2 * E_ + ((lane >= 32) ? E_ : 0);
  const int  ebl  = (eb & 31) * 1024;
  const ushort* sAsel = (lane & 16) ? sA1 : sA0;   // per-lane table select

  // ---- prefetch ALL edge indices ----
  int nidx[8][2];
#pragma unroll
  for (int b = 0; b < 8; b++)
#pragma unroll
    for (int ti = 0; ti < 2; ti++)
      nidx[b][ti] = ip[ebl + b * 128 + wave * 32 + ti * 16 + lm];

  bf16x8 xf[2];
#pragma unroll
  for (int ti = 0; ti < 2; ti++)
    xf[ti] = *(const bf16x8*)&sAsel[nidx[0][ti] * 8];

#pragma unroll
  for (int bi = 0; bi < 8; bi++) {
    // ---- prefetch next gather (hides LDS latency under this batch) ----
    bf16x8 xn[2];
    if (bi < 7) {
#pragma unroll
      for (int ti = 0; ti < 2; ti++)
        xn[ti] = *(const bf16x8*)&sAsel[nidx[bi + 1][ti] * 8];
    }

    // ---- L1: D = W1^T @ X^T (bias via C-operand) ----
    f32x4 acc1[2][4];
#pragma unroll
    for (int tj = 0; tj < 4; tj++)
#pragma unroll
      for (int ti = 0; ti < 2; ti++)
        acc1[ti][tj] = MFMA(fW1[tj], xf[ti], b1q[tj]);
    bf16x8 xf2[2][2];
#pragma unroll
    for (int ti = 0; ti < 2; ti++)
      relu_pack_shuf(acc1[ti], la, lbn, lo32, xf2[ti]);

    // ---- L2 ----
    f32x4 acc2[2][4];
#pragma unroll
    for (int ti = 0; ti < 2; ti++)
#pragma unroll
      for (int tj = 0; tj < 4; tj++)
        acc2[ti][tj] = b2q[tj];
#pragma unroll
    for (int ks = 0; ks < 2; ks++)
#pragma unroll
      for (int tj = 0; tj < 4; tj++)
#pragma unroll
        for (int ti = 0; ti < 2; ti++)
          acc2[ti][tj] = MFMA(fW2[tj][ks], xf2[ti][ks], acc2[ti][tj]);
    bf16x8 xf3[2][2];
#pragma unroll
    for (int ti = 0; ti < 2; ti++)
      relu_pack_shuf(acc2[ti], la, lbn, lo32, xf3[ti]);

    // ---- L3 + sigmoid ----
#pragma unroll
    for (int ti = 0; ti < 2; ti++) {
      f32x4 a3 = boq;
#pragma unroll
      for (int ks = 0; ks < 2; ks++)
        a3 = MFMA(fW3[ks], xf3[ti][ks], a3);
      float o[4];
#pragma unroll
      for (int r = 0; r < 4; r++)
        o[r] = 1.f / (1.f + __expf(-a3[r]));
      size_t base = (size_t)(eb * 1024 + bi * 128 + wave * 32 + ti * 16 + lm) * 10;
      if (q == 0) {
        float2 t0; t0.x = o[0]; t0.y = o[1]; *(float2*)(out_edge + base)     = t0;
        float2 t1; t1.x = o[2]; t1.y = o[3]; *(float2*)(out_edge + base + 2) = t1;
      } else if (q == 1) {
        float2 t0; t0.x = o[0]; t0.y = o[1]; *(float2*)(out_edge + base + 4) = t0;
        float2 t1; t1.x = o[2]; t1.y = o[3]; *(float2*)(out_edge + base + 6) = t1;
      } else if (q == 2) {
        float2 t0; t0.x = o[0]; t0.y = o[1]; *(float2*)(out_edge + base + 8) = t0;
      }
    }
    xf[0] = xn[0]; xf[1] = xn[1];
  }
}

// ---------------------------------------------------------------------------
// fused tail, double-buffered (round-5/6 config, unchanged).
// ---------------------------------------------------------------------------
#define STAGE_A(bufA, bufB, k0) do {                                        \
    { int c_ = tid >> 7, row_ = (tid >> 2) & 31;                            \
      GLDS(h1 + (size_t)(m0 + row_) * 512 + (k0) + c_ * 32 + skq,           \
           (char*)(bufA) + wave * 1024); }                                  \
    _Pragma("unroll")                                                       \
    for (int it = 0; it < 4; it++)                                          \
      _Pragma("unroll")                                                     \
      for (int c = 0; c < 2; c++)                                           \
        GLDS(w2t + (size_t)(it * 64 + srow) * 512 + (k0) + c * 32 + skq,    \
             (char*)(bufB) + c * 16384 + it * 4096 + wave * 1024);          \
  } while (0)

#define COMP_A(bufA, bufB) do {                                             \
    _Pragma("unroll")                                                       \
    for (int c = 0; c < 2; c++) {                                           \
      bf16x8 af = *(const bf16x8*)&((const short*)(bufA))                   \
          [c * 1024 + (wm * 16 + lm) * 32 + sq];                            \
      _Pragma("unroll")                                                     \
      for (int nt = 0; nt < 8; nt++) {                                      \
        bf16x8 bfr = *(const bf16x8*)&((const short*)(bufB))                \
            [c * 8192 + (wn * 128 + nt * 16 + lm) * 32 + sq];               \
        acc2[nt] = MFMA(af, bfr, acc2[nt]);                                 \
      } } } while (0)

#define STAGE_B(bufB, k0) do {                                              \
    _Pragma("unroll")                                                       \
    for (int it = 0; it < 2; it++)                                          \
      _Pragma("unroll")                                                     \
      for (int c = 0; c < 2; c++)                                           \
        GLDS(w3t + (size_t)(it * 64 + srow) * 256 + (k0) + c * 32 + skq,    \
             (char*)(bufB) + c * 8192 + it * 4096 + wave * 1024);           \
  } while (0)

#define COMP_B(bufB, k0) do {                                               \
    _Pragma("unroll")                                                       \
    for (int c = 0; c < 2; c++) {                                           \
      bf16x8 af = *(const bf16x8*)&sH2[(wm * 16 + lm) * 264                 \
          + (k0) + c * 32 + q * 8];                                         \
      _Pragma("unroll")                                                     \
      for (int nt = 0; nt < 4; nt++) {                                      \
        bf16x8 bfr = *(const bf16x8*)&((const short*)(bufB))                \
            [c * 4096 + (wn * 64 + nt * 16 + lm) * 32 + sq];                \
        acc3[nt] = MFMA(af, bfr, acc3[nt]);                                 \
      } } } while (0)

__global__ __launch_bounds__(256) void k_tail(
    const short* __restrict__ h1, const short* __restrict__ w2t,
    const short* __restrict__ w3t,
    const float* __restrict__ b2, const float* __restrict__ g2,
    const float* __restrict__ bb2, const float* __restrict__ rm2,
    const float* __restrict__ rv2,
    const float* __restrict__ b3, const float* __restrict__ niw,
    const float* __restrict__ nib, float* __restrict__ out)
{
  __shared__ __align__(16) char arena[73728];
  char* const A0 = arena;          char* const A1 = arena + 4096;
  char* const Bb0 = arena + 8192;  char* const Bb1 = arena + 40960;
  char* const B3a = arena + 20480; char* const B3b = arena + 36864;
  short* sH2 = (short*)arena;
  short* sH3 = (short*)(arena + 53248);

  const int tid  = threadIdx.x;
  const int wave = tid >> 6, lane = tid & 63;
  const int lm = lane & 15, q = lane >> 4;
  const int wm = wave >> 1, wn = wave & 1;
  const int m0 = blockIdx.x * 32;
  const int srow = tid >> 2;
  const int skq  = ((tid & 3) ^ ((tid >> 3) & 3)) * 8;
  const int sq   = (q ^ ((lm >> 1) & 3)) * 8;

  f32x4 acc2[8] = {};
  STAGE_A(A0, Bb0, 0);
  __syncthreads();
#pragma unroll
  for (int t = 0; t < 8; t += 2) {
    if (t + 1 < 8) STAGE_A(A1, Bb1, (t + 1) * 64);
    COMP_A(A0, Bb0);
    __syncthreads();
    if (t + 2 < 8) STAGE_A(A0, Bb0, (t + 2) * 64);
    COMP_A(A1, Bb1);
    __syncthreads();
  }
#pragma unroll
  for (int nt = 0; nt < 8; nt++) {
    int col = wn * 128 + nt * 16 + lm;
    float s = g2[col] * rsqrtf(rv2[col] + BN_EPSF);
    float t = bb2[col] - rm2[col] * s;
    float bi = b2[col];
    float v0 = fmaf(acc2[nt][0] + bi, s, t);
    float v1 = fmaf(acc2[nt][1] + bi, s, t);
    float v2 = fmaf(acc2[nt][2] + bi, s, t);
    float v3 = fmaf(acc2[nt][3] + bi, s, t);
    unsigned p01 = cvtpk(fmaxf(v0, 0.f), fmaxf(v1, 0.f));
    unsigned p23 = cvtpk(fmaxf(v2, 0.f), fmaxf(v3, 0.f));
    int rb = wm * 16 + q * 4;
    sH2[(rb + 0) * 264 + col] = (short)p01;
    sH2[(rb + 1) * 264 + col] = (short)(p01 >> 16);
    sH2[(rb + 2) * 264 + col] = (short)p23;
    sH2[(rb + 3) * 264 + col] = (short)(p23 >> 16);
  }
  STAGE_B(B3a, 0);
  __syncthreads();   // sH2 visible + B3a staged

  f32x4 acc3[4] = {};
#pragma unroll
  for (int t = 0; t < 4; t += 2) {
    if (t + 1 < 4) STAGE_B(B3b, (t + 1) * 64);
    COMP_B(B3a, t * 64);
    __syncthreads();
    if (t + 2 < 4) STAGE_B(B3a, (t + 2) * 64);
    COMP_B(B3b, (t + 1) * 64);
    __syncthreads();
  }
#pragma unroll
  for (int nt = 0; nt < 4; nt++) {
    int col = wn * 64 + nt * 16 + lm;
    float bi = b3[col];
    float v0 = acc3[nt][0] + bi;
    float v1 = acc3[nt][1] + bi;
    float v2 = acc3[nt][2] + bi;
    float v3 = acc3[nt][3] + bi;
    unsigned p01 = cvtpk(fmaxf(v0, 0.f), fmaxf(v1, 0.f));
    unsigned p23 = cvtpk(fmaxf(v2, 0.f), fmaxf(v3, 0.f));
    int rb = wm * 16 + q * 4;
    sH3[(rb + 0) * 136 + col] = (short)p01;
    sH3[(rb + 1) * 136 + col] = (short)(p01 >> 16);
    sH3[(rb + 2) * 136 + col] = (short)p23;
    sH3[(rb + 3) * 136 + col] = (short)(p23 >> 16);
  }
  __syncthreads();

  if (wave < 2) {
    f32x4 a4 = {};
#pragma unroll
    for (int c = 0; c < 4; c++) {
      ushort tmp[8];
#pragma unroll
      for (int j = 0; j < 8; j++) {
        int k = c * 32 + q * 8 + j;
        tmp[j] = (lm < 8) ? (ushort)f2bf(niw[k * 8 + lm]) : (ushort)0;
      }
      bf16x8 fw = *(bf16x8*)tmp;
      bf16x8 af4 = *(const bf16x8*)&sH3[(wave * 16 + lm) * 136 + c * 32 + q * 8];
      a4 = MFMA(af4, fw, a4);
    }
    if (lm < 8) {
      float bi = nib[lm];
#pragma unroll
      for (int r = 0; r < 4; r++) {
        float v = a4[r] + bi;
        out[(size_t)(m0 + wave * 16 + q * 4 + r) * 8 + lm] = 1.f / (1.f + __expf(-v));
      }
    }
  }
}

// ---------------------------------------------------------------------------
extern "C" void kernel_launch(void* const* d_in, const int* in_sizes, int n_in,
                              void* d_out, int out_size, void* d_ws, size_t ws_size,
                              hipStream_t stream)
{
  const float* roi   = (const float*)d_in[0];
  const float* bbox  = (const float*)d_in[1];
  const float* dir   = (const float*)d_in[2];
  const float* pri   = (const float*)d_in[3];
  const int*   eidx  = (const int*)d_in[4];
  const float* w1    = (const float*)d_in[5];
  const float* b1    = (const float*)d_in[6];
  const float* g1    = (const float*)d_in[7];
  const float* bb1   = (const float*)d_in[8];
  const float* rm1   = (const float*)d_in[9];
  const float* rv1   = (const float*)d_in[10];
  const float* w2    = (const float*)d_in[11];
  const float* b2    = (const float*)d_in[12];
  const float* g2    = (const float*)d_in[13];
  const float* bb2   = (const float*)d_in[14];
  const float* rm2   = (const float*)d_in[15];
  const float* rv2   = (const float*)d_in[16];
  const float* w3    = (const float*)d_in[17];
  const float* b3    = (const float*)d_in[18];
  const float* niw   = (const float*)d_in[19];
  const float* nib   = (const float*)d_in[20];
  const float* ew1   = (const float*)d_in[21];
  const float* eb1   = (const float*)d_in[22];
  const float* ew2   = (const float*)d_in[23];
  const float* eb2   = (const float*)d_in[24];
  const float* eow   = (const float*)d_in[25];
  const float* eob   = (const float*)d_in[26];

  float* out_node = (float*)d_out;                    // 16384 x 8
  float* out_edge = (float*)d_out + (size_t)M_ * NC_; // 1048576 x 10

  // workspace layout (bytes)
  char* w = (char*)d_ws;
  short*  roiB  = (short*)w;                          // 33,554,432
  short*  w1t   = (short*)(w + 33554432);             //  1,048,576
  short*  w2t   = (short*)(w + 34603008);             //    262,144
  short*  w3t   = (short*)(w + 34865152);             //     65,536
  ushort* attrT = (ushort*)(w + 34930688);            //    524,288 (gap)
  short*  h1    = (short*)(w + 35717120);             // 16,777,216

  // launch 1: conversions (roi bf16 + weight transposes + attr pack)
  k_prep<<<8928, 256, 0, stream>>>(roi, (ushort*)roiB, w1, w1t, w2, w2t,
                                   w3, w3t, bbox, dir, pri, attrT);

  // launch 2: fused edge MLP + node L1 GEMM (independent, 2:1 interleave)
  k_fused<<<1536, 256, 0, stream>>>(
      attrT, eidx, ew1, eb1, ew2, eb2, eow, eob, out_edge,
      roiB, w1t, b1, g1, bb1, rm1, rv1, h1);

  // launch 3: fused L2+L3+head (double-buffered)
  k_tail<<<M_ / 32, 256, 0, stream>>>(
      h1, w2t, w3t, b2, g2, bb2, rm2, rv2, b3, niw, nib, out_node);
}

// Round 8
// 234.855 us; speedup vs baseline: 1.9715x; 1.9715x over previous
//
#include <hip/hip_runtime.h>
#include <cstdint>
#include <cstddef>

#define BN_EPSF 1e-5f

constexpr int B_  = 32, N_ = 512, F_ = 1024, E_ = 32768;
constexpr int H1_ = 512, H2_ = 256, H3_ = 128, NC_ = 8, EC_ = 10;
constexpr int M_  = B_ * N_;      // 16384 node rows
constexpr int NE_ = B_ * E_;      // 1048576 edges

typedef short bf16x8 __attribute__((ext_vector_type(8)));
typedef float f32x4  __attribute__((ext_vector_type(4)));

__device__ __forceinline__ short f2bf(float f) {
  union { float f; unsigned u; } v; v.f = f;
  unsigned r = v.u + 0x7fffu + ((v.u >> 16) & 1u);   // RNE
  return (short)(r >> 16);
}
// HW packed f32->bf16 RNE: a -> low16, b -> high16
__device__ __forceinline__ unsigned cvtpk(float a, float b) {
  unsigned r;
  asm("v_cvt_pk_bf16_f32 %0, %1, %2" : "=v"(r) : "v"(a), "v"(b));
  return r;
}

#define GLDS(gp, lp) __builtin_amdgcn_global_load_lds( \
    (const __attribute__((address_space(1))) void*)(gp), \
    (__attribute__((address_space(3))) void*)(lp), 16, 0, 0)

#define MFMA(a, b, c) __builtin_amdgcn_mfma_f32_16x16x32_bf16((a), (b), (c), 0, 0, 0)

// ---------------------------------------------------------------------------
// prep: roi fp32->bf16 (8192) | 3x weight transpose (672) | attr pack (64).
// ---------------------------------------------------------------------------
__device__ __forceinline__ void wt_body(
    const float* __restrict__ W, short* __restrict__ Wt, int K, int N,
    int bx, int by, float (*s)[33])
{
  const int tx = threadIdx.x & 31, ty = threadIdx.x >> 5;
  const int k0 = by * 32, n0 = bx * 32;
#pragma unroll
  for (int r = 0; r < 4; r++)
    s[ty * 4 + r][tx] = W[(size_t)(k0 + ty * 4 + r) * N + n0 + tx];
  __syncthreads();
#pragma unroll
  for (int r = 0; r < 4; r++)
    Wt[(size_t)(n0 + ty * 4 + r) * K + k0 + tx] = f2bf(s[tx][ty * 4 + r]);
}

__global__ __launch_bounds__(256) void k_prep(
    const float* __restrict__ roi, ushort* __restrict__ roiB,
    const float* __restrict__ w1, short* __restrict__ w1t,
    const float* __restrict__ w2, short* __restrict__ w2t,
    const float* __restrict__ w3, short* __restrict__ w3t,
    const float* __restrict__ bbox, const float* __restrict__ dir,
    const float* __restrict__ pri, ushort* __restrict__ attrT)
{
  __shared__ float s[32][33];
  const int bx = blockIdx.x;
  if (bx < 8192) {                       // roi -> bf16, 8 elems/thread
    int i = bx * 256 + threadIdx.x;
    float4 a = *(const float4*)(roi + (size_t)i * 8);
    float4 b = *(const float4*)(roi + (size_t)i * 8 + 4);
    unsigned o[4];
    o[0] = cvtpk(a.x, a.y); o[1] = cvtpk(a.z, a.w);
    o[2] = cvtpk(b.x, b.y); o[3] = cvtpk(b.z, b.w);
    *(uint4*)(roiB + (size_t)i * 8) = *(uint4*)o;
  } else if (bx < 8704) {                // w1t: K=1024 N=512
    int idx = bx - 8192; wt_body(w1, w1t, F_, H1_, idx & 15, idx >> 4, s);
  } else if (bx < 8832) {                // w2t: K=512 N=256
    int idx = bx - 8704; wt_body(w2, w2t, H1_, H2_, idx & 7, idx >> 3, s);
  } else if (bx < 8864) {                // w3t: K=256 N=128
    int idx = bx - 8832; wt_body(w3, w3t, H2_, H3_, idx & 3, idx >> 2, s);
  } else {                               // attr pack: 1 node/thread
    int gi = (bx - 8864) * 256 + threadIdx.x;
    const float inv = 1.0f / 1024.0f;
    float4 bv = *(const float4*)(bbox + (size_t)gi * 4);
    float4 dv = *(const float4*)(dir + (size_t)gi * 4);
    float pp = pri[gi];
    uint4 lo, hi;
    lo.x = cvtpk(bv.x * inv, bv.y * inv); lo.y = cvtpk(bv.z * inv, bv.w * inv);
    lo.z = cvtpk(dv.x, dv.y);             lo.w = cvtpk(dv.z, dv.w);
    hi.x = cvtpk(pp, 0.f); hi.y = 0; hi.z = 0; hi.w = 0;
    *(uint4*)(attrT + (size_t)gi * 16)     = lo;
    *(uint4*)(attrT + (size_t)gi * 16 + 8) = hi;
  }
}

// ---------------------------------------------------------------------------
// Edge-path layer transition, fully in registers.
// ---------------------------------------------------------------------------
__device__ __forceinline__ void relu_pack_shuf(
    const f32x4 (&acc)[4], int la, int lb, bool lo32, bf16x8 (&out)[2])
{
  unsigned plo[4], phi[4];
#pragma unroll
  for (int t = 0; t < 4; t++) {
    plo[t] = cvtpk(fmaxf(acc[t][0], 0.f), fmaxf(acc[t][1], 0.f));
    phi[t] = cvtpk(fmaxf(acc[t][2], 0.f), fmaxf(acc[t][3], 0.f));
  }
#pragma unroll
  for (int ks = 0; ks < 2; ks++) {
    unsigned w0a = (unsigned)__shfl((int)plo[2 * ks], la);
    unsigned w0b = (unsigned)__shfl((int)plo[2 * ks + 1], la);
    unsigned w1a = (unsigned)__shfl((int)phi[2 * ks], la);
    unsigned w1b = (unsigned)__shfl((int)phi[2 * ks + 1], la);
    unsigned w2a = (unsigned)__shfl((int)plo[2 * ks], lb);
    unsigned w2b = (unsigned)__shfl((int)plo[2 * ks + 1], lb);
    unsigned w3a = (unsigned)__shfl((int)phi[2 * ks], lb);
    unsigned w3b = (unsigned)__shfl((int)phi[2 * ks + 1], lb);
    union { unsigned u[4]; bf16x8 v; } t;
    t.u[0] = lo32 ? w0a : w0b;
    t.u[1] = lo32 ? w1a : w1b;
    t.u[2] = lo32 ? w2a : w2b;
    t.u[3] = lo32 ? w3a : w3b;
    out[ks] = t.v;
  }
}

// ---------------------------------------------------------------------------
// fused edge+L1 kernel. Grid 1536, 2:1 interleave. L1: BK=64 + chunk-XOR
// swizzle (R4-verified). Edge: split 16B-row attr tables (R7-verified
// correct). launch_bounds (256,3): R7's (256,5) forced VGPR 84->48 and
// spilled ~600MB/launch to scratch (FETCH 74->484MB) -- NEVER cap VGPR
// below the kernel's natural allocation. Arena 32KB.
// ---------------------------------------------------------------------------
__global__ __launch_bounds__(256, 3) void k_fused(
    // edge args
    const ushort* __restrict__ attrT, const int* __restrict__ eidx,
    const float* __restrict__ ew1, const float* __restrict__ eb1,
    const float* __restrict__ ew2, const float* __restrict__ eb2,
    const float* __restrict__ eow, const float* __restrict__ eob,
    float* __restrict__ out_edge,
    // L1 args
    const short* __restrict__ roiB, const short* __restrict__ w1t,
    const float* __restrict__ b1, const float* __restrict__ g1,
    const float* __restrict__ bb1, const float* __restrict__ rm1,
    const float* __restrict__ rv1, short* __restrict__ h1)
{
  __shared__ __align__(16) char arena[32768];

  const int bx = blockIdx.x;
  const int rsel = bx % 3;
  const int tid  = threadIdx.x;
  const int wave = tid >> 6, lane = tid & 63;
  const int lm = lane & 15;

  if (rsel == 2) {
    // ================= L1 GEMM block (BK=64, swizzled) =================
    const int lb = bx / 3;
    short* As = (short*)arena;             // 128 x 64 (128B rows, swizzled)
    short* Bs = (short*)(arena + 16384);   // 128 x 64
    const int m0 = (lb >> 2) * 128, n0 = (lb & 3) * 128;
    const int wm = wave >> 1, wn = wave & 1;
    const int q  = lane >> 4;
    const int srow = tid >> 3;
    const int sko  = ((tid & 7) ^ (srow & 7)) * 8;

    f32x4 acc[4][4] = {};
    for (int k0 = 0; k0 < F_; k0 += 64) {
#pragma unroll
      for (int it = 0; it < 4; it++)
        GLDS(roiB + (size_t)(m0 + it * 32 + srow) * F_ + k0 + sko,
             (char*)As + it * 4096 + wave * 1024);
#pragma unroll
      for (int it = 0; it < 4; it++)
        GLDS(w1t + (size_t)(n0 + it * 32 + srow) * F_ + k0 + sko,
             (char*)Bs + it * 4096 + wave * 1024);
      __syncthreads();

#pragma unroll
      for (int ks = 0; ks < 2; ks++) {
        const int co = (((ks * 4 + q) ^ (lm & 7)) * 8);   // swizzled k-chunk
        bf16x8 af[4], bfr[4];
#pragma unroll
        for (int t = 0; t < 4; t++) {
          af[t]  = *(const bf16x8*)&As[(wm * 64 + t * 16 + lm) * 64 + co];
          bfr[t] = *(const bf16x8*)&Bs[(wn * 64 + t * 16 + lm) * 64 + co];
        }
#pragma unroll
        for (int ti = 0; ti < 4; ti++)
#pragma unroll
          for (int tj = 0; tj < 4; tj++)
            acc[ti][tj] = MFMA(af[ti], bfr[tj], acc[ti][tj]);
      }
      __syncthreads();
    }
#pragma unroll
    for (int tj = 0; tj < 4; tj++) {
      const int col = n0 + wn * 64 + tj * 16 + lm;
      const float bi = b1[col];
      float s = g1[col] * rsqrtf(rv1[col] + BN_EPSF);
      float t = bb1[col] - rm1[col] * s;
#pragma unroll
      for (int ti = 0; ti < 4; ti++) {
        const int rbase = m0 + wm * 64 + ti * 16 + ((lane >> 4) << 2);
#pragma unroll
        for (int r = 0; r < 4; r += 2) {
          float va = fmaf(acc[ti][tj][r]     + bi, s, t);
          float vb = fmaf(acc[ti][tj][r + 1] + bi, s, t);
          unsigned p = cvtpk(fmaxf(va, 0.f), fmaxf(vb, 0.f));
          h1[(size_t)(rbase + r)     * H1_ + col] = (short)p;
          h1[(size_t)(rbase + r + 1) * H1_ + col] = (short)(p >> 16);
        }
      }
    }
    return;
  }

  // ================= edge block =================
  const int eb    = (bx / 3) * 2 + rsel;     // 0..1023
  const int batch = eb >> 5;                 // one graph-batch per block
  const int q     = lane >> 4;

  short*  sW1 = (short*)arena;               // 64 x 32 (K remapped/padded)
  short*  sW2 = (short*)(arena + 4096);      // 64 x 64
  short*  sW3 = (short*)(arena + 12288);     // 16 x 64 (rows 10..15 zero)
  ushort* sA0 = (ushort*)(arena + 14336);    // 512 x 8: node attr chunk 0
  ushort* sA1 = (ushort*)(arena + 22528);    // 512 x 8: node attr chunk 1

  // ---- stage weights + split attr tables (once per block) ----
  // W1 K-layout: k<9 = src attrs, 16<=k<25 = dst attrs, rest zero.
  for (int i = tid; i < 2048; i += 256) {
    int n = i >> 5, k = i & 31;
    short v = 0;
    if (k < 9)                  v = f2bf(ew1[k * 64 + n]);
    else if (k >= 16 && k < 25) v = f2bf(ew1[(k - 7) * 64 + n]);
    sW1[i] = v;
  }
  for (int i = tid; i < 4096; i += 256) {
    int n = i >> 6, k = i & 63;
    sW2[i] = f2bf(ew2[k * 64 + n]);
  }
  for (int i = tid; i < 1024; i += 256) {
    int n = i >> 6, k = i & 63;
    sW3[i] = (n < 10) ? f2bf(eow[k * 10 + n]) : (short)0;
  }
  {
    const ushort* atg = attrT + (size_t)batch * 512 * 16;
    for (int n = tid; n < 512; n += 256) {
      uint4 lo = *(const uint4*)(atg + n * 16);
      uint4 hi = *(const uint4*)(atg + n * 16 + 8);
      *(uint4*)&sA0[n * 8] = lo;
      *(uint4*)&sA1[n * 8] = hi;
    }
  }
  __syncthreads();   // the ONLY barrier in this block

  // ---- weight fragments + biases into registers (ONCE per block) ----
  bf16x8 fW1[4], fW2[4][2], fW3[2];
#pragma unroll
  for (int t = 0; t < 4; t++)
    fW1[t] = *(const bf16x8*)&sW1[(t * 16 + lm) * 32 + q * 8];
#pragma unroll
  for (int t = 0; t < 4; t++)
#pragma unroll
    for (int ks = 0; ks < 2; ks++)
      fW2[t][ks] = *(const bf16x8*)&sW2[(t * 16 + lm) * 64 + ks * 32 + q * 8];
#pragma unroll
  for (int ks = 0; ks < 2; ks++)
    fW3[ks] = *(const bf16x8*)&sW3[lm * 64 + ks * 32 + q * 8];

  f32x4 b1q[4], b2q[4], boq;
#pragma unroll
  for (int t = 0; t < 4; t++) {
    b1q[t] = *(const f32x4*)(eb1 + t * 16 + q * 4);
    b2q[t] = *(const f32x4*)(eb2 + t * 16 + q * 4);
  }
#pragma unroll
  for (int r = 0; r < 4; r++)
    boq[r] = (q * 4 + r < 10) ? eob[q * 4 + r] : 0.f;

  const int  la   = (lane & 15) | ((lane & 16) << 1);   // e + 32*(kq&1)
  const int  lbn  = la + 16;
  const bool lo32 = (lane < 32);
  const int* ip   = eidx + (size_t)batch * 2 * E_ + ((lane >= 32) ? E_ : 0);
  const int  ebl  = (eb & 31) * 1024;
  const ushort* sAsel = (lane & 16) ? sA1 : sA0;   // per-lane table select

  // ---- prefetch ALL edge indices ----
  int nidx[8][2];
#pragma unroll
  for (int b = 0; b < 8; b++)
#pragma unroll
    for (int ti = 0; ti < 2; ti++)
      nidx[b][ti] = ip[ebl + b * 128 + wave * 32 + ti * 16 + lm];

  bf16x8 xf[2];
#pragma unroll
  for (int ti = 0; ti < 2; ti++)
    xf[ti] = *(const bf16x8*)&sAsel[nidx[0][ti] * 8];

#pragma unroll
  for (int bi = 0; bi < 8; bi++) {
    // ---- prefetch next gather (hides LDS latency under this batch) ----
    bf16x8 xn[2];
    if (bi < 7) {
#pragma unroll
      for (int ti = 0; ti < 2; ti++)
        xn[ti] = *(const bf16x8*)&sAsel[nidx[bi + 1][ti] * 8];
    }

    // ---- L1: D = W1^T @ X^T (bias via C-operand) ----
    f32x4 acc1[2][4];
#pragma unroll
    for (int tj = 0; tj < 4; tj++)
#pragma unroll
      for (int ti = 0; ti < 2; ti++)
        acc1[ti][tj] = MFMA(fW1[tj], xf[ti], b1q[tj]);
    bf16x8 xf2[2][2];
#pragma unroll
    for (int ti = 0; ti < 2; ti++)
      relu_pack_shuf(acc1[ti], la, lbn, lo32, xf2[ti]);

    // ---- L2 ----
    f32x4 acc2[2][4];
#pragma unroll
    for (int ti = 0; ti < 2; ti++)
#pragma unroll
      for (int tj = 0; tj < 4; tj++)
        acc2[ti][tj] = b2q[tj];
#pragma unroll
    for (int ks = 0; ks < 2; ks++)
#pragma unroll
      for (int tj = 0; tj < 4; tj++)
#pragma unroll
        for (int ti = 0; ti < 2; ti++)
          acc2[ti][tj] = MFMA(fW2[tj][ks], xf2[ti][ks], acc2[ti][tj]);
    bf16x8 xf3[2][2];
#pragma unroll
    for (int ti = 0; ti < 2; ti++)
      relu_pack_shuf(acc2[ti], la, lbn, lo32, xf3[ti]);

    // ---- L3 + sigmoid ----
#pragma unroll
    for (int ti = 0; ti < 2; ti++) {
      f32x4 a3 = boq;
#pragma unroll
      for (int ks = 0; ks < 2; ks++)
        a3 = MFMA(fW3[ks], xf3[ti][ks], a3);
      float o[4];
#pragma unroll
      for (int r = 0; r < 4; r++)
        o[r] = 1.f / (1.f + __expf(-a3[r]));
      size_t base = (size_t)(eb * 1024 + bi * 128 + wave * 32 + ti * 16 + lm) * 10;
      if (q == 0) {
        float2 t0; t0.x = o[0]; t0.y = o[1]; *(float2*)(out_edge + base)     = t0;
        float2 t1; t1.x = o[2]; t1.y = o[3]; *(float2*)(out_edge + base + 2) = t1;
      } else if (q == 1) {
        float2 t0; t0.x = o[0]; t0.y = o[1]; *(float2*)(out_edge + base + 4) = t0;
        float2 t1; t1.x = o[2]; t1.y = o[3]; *(float2*)(out_edge + base + 6) = t1;
      } else if (q == 2) {
        float2 t0; t0.x = o[0]; t0.y = o[1]; *(float2*)(out_edge + base + 8) = t0;
      }
    }
    xf[0] = xn[0]; xf[1] = xn[1];
  }
}

// ---------------------------------------------------------------------------
// fused tail, double-buffered (round-5/6 config, unchanged).
// ---------------------------------------------------------------------------
#define STAGE_A(bufA, bufB, k0) do {                                        \
    { int c_ = tid >> 7, row_ = (tid >> 2) & 31;                            \
      GLDS(h1 + (size_t)(m0 + row_) * 512 + (k0) + c_ * 32 + skq,           \
           (char*)(bufA) + wave * 1024); }                                  \
    _Pragma("unroll")                                                       \
    for (int it = 0; it < 4; it++)                                          \
      _Pragma("unroll")                                                     \
      for (int c = 0; c < 2; c++)                                           \
        GLDS(w2t + (size_t)(it * 64 + srow) * 512 + (k0) + c * 32 + skq,    \
             (char*)(bufB) + c * 16384 + it * 4096 + wave * 1024);          \
  } while (0)

#define COMP_A(bufA, bufB) do {                                             \
    _Pragma("unroll")                                                       \
    for (int c = 0; c < 2; c++) {                                           \
      bf16x8 af = *(const bf16x8*)&((const short*)(bufA))                   \
          [c * 1024 + (wm * 16 + lm) * 32 + sq];                            \
      _Pragma("unroll")                                                     \
      for (int nt = 0; nt < 8; nt++) {                                      \
        bf16x8 bfr = *(const bf16x8*)&((const short*)(bufB))                \
            [c * 8192 + (wn * 128 + nt * 16 + lm) * 32 + sq];               \
        acc2[nt] = MFMA(af, bfr, acc2[nt]);                                 \
      } } } while (0)

#define STAGE_B(bufB, k0) do {                                              \
    _Pragma("unroll")                                                       \
    for (int it = 0; it < 2; it++)                                          \
      _Pragma("unroll")                                                     \
      for (int c = 0; c < 2; c++)                                           \
        GLDS(w3t + (size_t)(it * 64 + srow) * 256 + (k0) + c * 32 + skq,    \
             (char*)(bufB) + c * 8192 + it * 4096 + wave * 1024);           \
  } while (0)

#define COMP_B(bufB, k0) do {                                               \
    _Pragma("unroll")                                                       \
    for (int c = 0; c < 2; c++) {                                           \
      bf16x8 af = *(const bf16x8*)&sH2[(wm * 16 + lm) * 264                 \
          + (k0) + c * 32 + q * 8];                                         \
      _Pragma("unroll")                                                     \
      for (int nt = 0; nt < 4; nt++) {                                      \
        bf16x8 bfr = *(const bf16x8*)&((const short*)(bufB))                \
            [c * 4096 + (wn * 64 + nt * 16 + lm) * 32 + sq];                \
        acc3[nt] = MFMA(af, bfr, acc3[nt]);                                 \
      } } } while (0)

__global__ __launch_bounds__(256) void k_tail(
    const short* __restrict__ h1, const short* __restrict__ w2t,
    const short* __restrict__ w3t,
    const float* __restrict__ b2, const float* __restrict__ g2,
    const float* __restrict__ bb2, const float* __restrict__ rm2,
    const float* __restrict__ rv2,
    const float* __restrict__ b3, const float* __restrict__ niw,
    const float* __restrict__ nib, float* __restrict__ out)
{
  __shared__ __align__(16) char arena[73728];
  char* const A0 = arena;          char* const A1 = arena + 4096;
  char* const Bb0 = arena + 8192;  char* const Bb1 = arena + 40960;
  char* const B3a = arena + 20480; char* const B3b = arena + 36864;
  short* sH2 = (short*)arena;
  short* sH3 = (short*)(arena + 53248);

  const int tid  = threadIdx.x;
  const int wave = tid >> 6, lane = tid & 63;
  const int lm = lane & 15, q = lane >> 4;
  const int wm = wave >> 1, wn = wave & 1;
  const int m0 = blockIdx.x * 32;
  const int srow = tid >> 2;
  const int skq  = ((tid & 3) ^ ((tid >> 3) & 3)) * 8;
  const int sq   = (q ^ ((lm >> 1) & 3)) * 8;

  f32x4 acc2[8] = {};
  STAGE_A(A0, Bb0, 0);
  __syncthreads();
#pragma unroll
  for (int t = 0; t < 8; t += 2) {
    if (t + 1 < 8) STAGE_A(A1, Bb1, (t + 1) * 64);
    COMP_A(A0, Bb0);
    __syncthreads();
    if (t + 2 < 8) STAGE_A(A0, Bb0, (t + 2) * 64);
    COMP_A(A1, Bb1);
    __syncthreads();
  }
#pragma unroll
  for (int nt = 0; nt < 8; nt++) {
    int col = wn * 128 + nt * 16 + lm;
    float s = g2[col] * rsqrtf(rv2[col] + BN_EPSF);
    float t = bb2[col] - rm2[col] * s;
    float bi = b2[col];
    float v0 = fmaf(acc2[nt][0] + bi, s, t);
    float v1 = fmaf(acc2[nt][1] + bi, s, t);
    float v2 = fmaf(acc2[nt][2] + bi, s, t);
    float v3 = fmaf(acc2[nt][3] + bi, s, t);
    unsigned p01 = cvtpk(fmaxf(v0, 0.f), fmaxf(v1, 0.f));
    unsigned p23 = cvtpk(fmaxf(v2, 0.f), fmaxf(v3, 0.f));
    int rb = wm * 16 + q * 4;
    sH2[(rb + 0) * 264 + col] = (short)p01;
    sH2[(rb + 1) * 264 + col] = (short)(p01 >> 16);
    sH2[(rb + 2) * 264 + col] = (short)p23;
    sH2[(rb + 3) * 264 + col] = (short)(p23 >> 16);
  }
  STAGE_B(B3a, 0);
  __syncthreads();   // sH2 visible + B3a staged

  f32x4 acc3[4] = {};
#pragma unroll
  for (int t = 0; t < 4; t += 2) {
    if (t + 1 < 4) STAGE_B(B3b, (t + 1) * 64);
    COMP_B(B3a, t * 64);
    __syncthreads();
    if (t + 2 < 4) STAGE_B(B3a, (t + 2) * 64);
    COMP_B(B3b, (t + 1) * 64);
    __syncthreads();
  }
#pragma unroll
  for (int nt = 0; nt < 4; nt++) {
    int col = wn * 64 + nt * 16 + lm;
    float bi = b3[col];
    float v0 = acc3[nt][0] + bi;
    float v1 = acc3[nt][1] + bi;
    float v2 = acc3[nt][2] + bi;
    float v3 = acc3[nt][3] + bi;
    unsigned p01 = cvtpk(fmaxf(v0, 0.f), fmaxf(v1, 0.f));
    unsigned p23 = cvtpk(fmaxf(v2, 0.f), fmaxf(v3, 0.f));
    int rb = wm * 16 + q * 4;
    sH3[(rb + 0) * 136 + col] = (short)p01;
    sH3[(rb + 1) * 136 + col] = (short)(p01 >> 16);
    sH3[(rb + 2) * 136 + col] = (short)p23;
    sH3[(rb + 3) * 136 + col] = (short)(p23 >> 16);
  }
  __syncthreads();

  if (wave < 2) {
    f32x4 a4 = {};
#pragma unroll
    for (int c = 0; c < 4; c++) {
      ushort tmp[8];
#pragma unroll
      for (int j = 0; j < 8; j++) {
        int k = c * 32 + q * 8 + j;
        tmp[j] = (lm < 8) ? (ushort)f2bf(niw[k * 8 + lm]) : (ushort)0;
      }
      bf16x8 fw = *(bf16x8*)tmp;
      bf16x8 af4 = *(const bf16x8*)&sH3[(wave * 16 + lm) * 136 + c * 32 + q * 8];
      a4 = MFMA(af4, fw, a4);
    }
    if (lm < 8) {
      float bi = nib[lm];
#pragma unroll
      for (int r = 0; r < 4; r++) {
        float v = a4[r] + bi;
        out[(size_t)(m0 + wave * 16 + q * 4 + r) * 8 + lm] = 1.f / (1.f + __expf(-v));
      }
    }
  }
}

// ---------------------------------------------------------------------------
extern "C" void kernel_launch(void* const* d_in, const int* in_sizes, int n_in,
                              void* d_out, int out_size, void* d_ws, size_t ws_size,
                              hipStream_t stream)
{
  const float* roi   = (const float*)d_in[0];
  const float* bbox  = (const float*)d_in[1];
  const float* dir   = (const float*)d_in[2];
  const float* pri   = (const float*)d_in[3];
  const int*   eidx  = (const int*)d_in[4];
  const float* w1    = (const float*)d_in[5];
  const float* b1    = (const float*)d_in[6];
  const float* g1    = (const float*)d_in[7];
  const float* bb1   = (const float*)d_in[8];
  const float* rm1   = (const float*)d_in[9];
  const float* rv1   = (const float*)d_in[10];
  const float* w2    = (const float*)d_in[11];
  const float* b2    = (const float*)d_in[12];
  const float* g2    = (const float*)d_in[13];
  const float* bb2   = (const float*)d_in[14];
  const float* rm2   = (const float*)d_in[15];
  const float* rv2   = (const float*)d_in[16];
  const float* w3    = (const float*)d_in[17];
  const float* b3    = (const float*)d_in[18];
  const float* niw   = (const float*)d_in[19];
  const float* nib   = (const float*)d_in[20];
  const float* ew1   = (const float*)d_in[21];
  const float* eb1   = (const float*)d_in[22];
  const float* ew2   = (const float*)d_in[23];
  const float* eb2   = (const float*)d_in[24];
  const float* eow   = (const float*)d_in[25];
  const float* eob   = (const float*)d_in[26];

  float* out_node = (float*)d_out;                    // 16384 x 8
  float* out_edge = (float*)d_out + (size_t)M_ * NC_; // 1048576 x 10

  // workspace layout (bytes)
  char* w = (char*)d_ws;
  short*  roiB  = (short*)w;                          // 33,554,432
  short*  w1t   = (short*)(w + 33554432);             //  1,048,576
  short*  w2t   = (short*)(w + 34603008);             //    262,144
  short*  w3t   = (short*)(w + 34865152);             //     65,536
  ushort* attrT = (ushort*)(w + 34930688);            //    524,288 (gap)
  short*  h1    = (short*)(w + 35717120);             // 16,777,216

  // launch 1: conversions (roi bf16 + weight transposes + attr pack)
  k_prep<<<8928, 256, 0, stream>>>(roi, (ushort*)roiB, w1, w1t, w2, w2t,
                                   w3, w3t, bbox, dir, pri, attrT);

  // launch 2: fused edge MLP + node L1 GEMM (independent, 2:1 interleave)
  k_fused<<<1536, 256, 0, stream>>>(
      attrT, eidx, ew1, eb1, ew2, eb2, eow, eob, out_edge,
      roiB, w1t, b1, g1, bb1, rm1, rv1, h1);

  // launch 3: fused L2+L3+head (double-buffered)
  k_tail<<<M_ / 32, 256, 0, stream>>>(
      h1, w2t, w3t, b2, g2, bb2, rm2, rv2, b3, niw, nib, out_node);
}